// Round 7
// baseline (697.882 us; speedup 1.0000x reference)
//
#include <hip/hip_runtime.h>
#include <math.h>

typedef unsigned short u16;
typedef unsigned int u32;
typedef short v8s __attribute__((ext_vector_type(8)));
typedef float v4f __attribute__((ext_vector_type(4)));

#define EMB 300
#define SP 320            // padded feature stride (bf16 elems)
#define NGRP 4096
#define FEAT 256
#define MT 96
#define NT 160
#define NCOMB 357         // 119 atom types x 3 chirality
#define NREP 32           // colstats replicas (atomic spread)
#define CSB (NREP * 2 * SP)   // floats per colstats bank

__device__ __forceinline__ u16 f2bf(float x) {
    u32 u = __float_as_uint(x);
    u += 0x7FFFu + ((u >> 16) & 1u);
    return (u16)(u >> 16);
}
__device__ __forceinline__ float bf2f(u16 h) {
    return __uint_as_float((u32)h << 16);
}
__device__ __forceinline__ void unpack8(uint4 w, float* o) {
    const u32* p = &w.x;
#pragma unroll
    for (int q = 0; q < 4; q++) {
        o[2 * q]     = __uint_as_float(p[q] << 16);
        o[2 * q + 1] = __uint_as_float(p[q] & 0xFFFF0000u);
    }
}
// clamp 8 packed bf16 against per-col bf16-exact thresholds (lossless repack)
// perm repack: dst = (lo>>16) | (hi & 0xFFFF0000)
__device__ __forceinline__ v8s clampA(uint4 w, float4 ta, float4 tb) {
    const u32* p = &w.x;
    float t[8] = {ta.x, ta.y, ta.z, ta.w, tb.x, tb.y, tb.z, tb.w};
    u32 o[4];
#pragma unroll
    for (int q = 0; q < 4; q++) {
        float lo = __uint_as_float(p[q] << 16);
        float hi = __uint_as_float(p[q] & 0xFFFF0000u);
        lo = fmaxf(lo, t[2 * q]);
        hi = fmaxf(hi, t[2 * q + 1]);
        o[q] = __builtin_amdgcn_perm(__float_as_uint(hi), __float_as_uint(lo),
                                     0x07060302u);
    }
    uint4 r = make_uint4(o[0], o[1], o[2], o[3]);
    return *(v8s*)&r;
}
// async global->LDS DMA, 16B per lane (dest = wave-uniform base + lane*16)
__device__ __forceinline__ void dma16(const u16* g, u16* l) {
    __builtin_amdgcn_global_load_lds(
        (const __attribute__((address_space(1))) unsigned int*)g,
        (__attribute__((address_space(3))) unsigned int*)l, 16, 0, 0);
}

// ---------- per-node prep: c9 map + zero deg/cursor + Q pad row --------------
__global__ void k_prep_n(const int* __restrict__ at, const int* __restrict__ ch,
                         int* __restrict__ c9, int* __restrict__ deg,
                         int* __restrict__ cursor, u16* __restrict__ Q, int N) {
    int n = blockIdx.x * blockDim.x + threadIdx.x;
    if (n < N) {
        c9[n] = at[n] * 3 + ch[n];
        deg[n] = 0;
        cursor[n] = 0;
    }
    // zero padding row Q[N] (gather target for out-of-range unroll slots)
    if (n < SP / 2) ((u32*)(Q + (size_t)N * SP))[n] = 0u;
}

// ---------- fused: edge count (CSR deg) + comb table build -------------------
__global__ void k_cntcomb(const int* __restrict__ col, int* __restrict__ deg, int E,
                          const float* __restrict__ e1, const float* __restrict__ e2,
                          u16* __restrict__ comb) {
    int i = blockIdx.x * blockDim.x + threadIdx.x;
    if (i < E) atomicAdd(&deg[col[i]], 1);
    if (i < NCOMB * 40) {
        int row = i / 40, f = i % 40;
        int at = row / 3, ch = row % 3;
        u32 o[4];
#pragma unroll
        for (int q = 0; q < 4; q++) {
            int c0 = f * 8 + q * 2;
            float x0 = 0.f, x1 = 0.f;
            if (c0 < EMB)     x0 = e1[(size_t)at * EMB + c0] + e2[(size_t)ch * EMB + c0];
            if (c0 + 1 < EMB) x1 = e1[(size_t)at * EMB + c0 + 1] + e2[(size_t)ch * EMB + c0 + 1];
            o[q] = (u32)f2bf(x0) | ((u32)f2bf(x1) << 16);
        }
        *(uint4*)(comb + (size_t)row * SP + f * 8) = make_uint4(o[0], o[1], o[2], o[3]);
    }
}

__global__ __launch_bounds__(256) void k_bsum(const int* __restrict__ deg,
                                              int* __restrict__ bsum, int N) {
    int base = blockIdx.x * 1024 + threadIdx.x * 4;
    int s = 0;
    if (base + 3 < N) {
        int4 v = *(const int4*)(deg + base);
        s = v.x + v.y + v.z + v.w;
    } else {
        for (int j = 0; j < 4; j++) if (base + j < N) s += deg[base + j];
    }
    __shared__ int red[256];
    red[threadIdx.x] = s;
    __syncthreads();
    for (int off = 128; off > 0; off >>= 1) {
        if (threadIdx.x < off) red[threadIdx.x] += red[threadIdx.x + off];
        __syncthreads();
    }
    if (threadIdx.x == 0) bsum[blockIdx.x] = red[0];
}

// indptr with block-offset scan fused in (each block redundantly scans bsum)
__global__ __launch_bounds__(256) void k_indptr(const int* __restrict__ deg,
                                                const int* __restrict__ bsum,
                                                int* __restrict__ indptr, int N, int NB) {
    __shared__ int bs[128];
    __shared__ int sh[256];
    int b = blockIdx.x, t = threadIdx.x;
    if (t < 128) bs[t] = (t < NB) ? bsum[t] : 0;
    __syncthreads();
    for (int off = 1; off < 128; off <<= 1) {
        int add = (t < 128 && t >= off) ? bs[t - off] : 0;
        __syncthreads();
        if (t < 128) bs[t] += add;
        __syncthreads();
    }
    int boffb = (b > 0) ? bs[b - 1] : 0;

    int base = b * 1024 + t * 4;
    int v[4] = {0, 0, 0, 0};
    if (base + 3 < N) {
        int4 w = *(const int4*)(deg + base);
        v[0] = w.x; v[1] = w.y; v[2] = w.z; v[3] = w.w;
    } else {
        for (int j = 0; j < 4; j++) if (base + j < N) v[j] = deg[base + j];
    }
    int tsum = v[0] + v[1] + v[2] + v[3];
    sh[t] = tsum;
    __syncthreads();
    for (int off = 1; off < 256; off <<= 1) {
        int add = (t >= off) ? sh[t - off] : 0;
        __syncthreads();
        sh[t] += add;
        __syncthreads();
    }
    int run = boffb + sh[t] - tsum;
    for (int j = 0; j < 4; j++) {
        run += v[j];
        if (base + j < N) indptr[base + j + 1] = run;
    }
    if (b == 0 && t == 0) indptr[0] = 0;
}

__global__ void k_fill(const int* __restrict__ row, const int* __restrict__ col,
                       const int* __restrict__ et, const int* __restrict__ ed,
                       const int* __restrict__ indptr, int* __restrict__ cursor,
                       int* __restrict__ packed, int E) {
    int e = blockIdx.x * blockDim.x + threadIdx.x;
    if (e >= E) return;
    int c = col[e];
    int pos = indptr[c] + atomicAdd(&cursor[c], 1);
    packed[pos] = row[e] | ((et[e] * 3 + ed[e]) << 17);
}

// ---- fused W prep: BN-finalize + Wt + srow + thr + zero next colstats bank --
__global__ __launch_bounds__(320) void k_wprep(
    const float* __restrict__ Wl, const float* __restrict__ cs,
    const float* __restrict__ gamma, const float* __restrict__ beta,
    int ident, int N, u16* __restrict__ Wt, float* __restrict__ srow,
    float* __restrict__ thr, float* __restrict__ wb) {
    __shared__ float wred[5];
    int n = blockIdx.x;
    int k = threadIdx.x;

    // zero the bank aggf(this layer) will write (blocks 0..63 cover CSB)
    int zi = n * 320 + k;
    if (zi < CSB) wb[zi] = 0.f;

    float scv, shv, thv;
    if (ident) {
        scv = (k < EMB) ? 1.f : 0.f;
        shv = 0.f;
        thv = -__builtin_inff();
    } else if (k < EMB) {
        float s1 = 0.f, s2 = 0.f;
        for (int r = 0; r < NREP; r++) {
            s1 += cs[r * 2 * SP + k];
            s2 += cs[r * 2 * SP + SP + k];
        }
        float inv = 1.f / (float)N;
        float mean = s1 * inv;
        float var = s2 * inv - mean * mean;
        float rstd = rsqrtf(fmaxf(var, 0.f) + 1e-5f);
        scv = gamma[k] * rstd;
        shv = beta[k] - mean * scv;
        thv = bf2f(f2bf(-shv / scv));
    } else {
        scv = 0.f; shv = 0.f; thv = -__builtin_inff();
    }
    if (n == 0) thr[k] = thv;

    float w = 0.f;
    if (n < EMB && k < EMB) w = Wl[(size_t)k * EMB + n];
    Wt[(size_t)n * SP + k] = f2bf(w * scv);
    float s = (k < EMB) ? shv * w : 0.f;
#pragma unroll
    for (int o2 = 32; o2 > 0; o2 >>= 1) s += __shfl_down(s, o2);
    if ((k & 63) == 0) wred[k >> 6] = s;
    __syncthreads();
    if (k == 0) {
        float t = wred[0] + wred[1] + wred[2] + wred[3] + wred[4];
        srow[n] = (n < EMB) ? t : 0.f;
    }
}

// ------------------- GEMM: Q = max(A[rowmap], thr) @ Wt + srow  ---------------
// v6: R2 schedule (BK=32, all-DMA double-buffer, clamp at read) with MT=96:
// LDS staging = A 2x6KB + B 2x10KB = exactly 32KB -> 5 blocks/CU (was 4).
// Per-wave fragments 3x5; single-pass epilogue (96x168 u16 = 31.5KB overlay).
__global__ __launch_bounds__(256) void k_gemm(
    const u16* __restrict__ A, const u16* __restrict__ Wt,
    const float* __restrict__ thr, const float* __restrict__ srow,
    u16* __restrict__ C, int M, const int* __restrict__ rowmap) {
    __shared__ __align__(16) u16 sm[16384];   // A 2x3072 | B 2x5120 ; epi 96x168

    int m0 = blockIdx.y * MT;
    int n0 = blockIdx.x * NT;
    int tid = threadIdx.x;
    int wave = tid >> 6, lane = tid & 63;
    int wm = wave >> 1, wn = wave & 1;
    int lm = lane & 15, quad = lane >> 4;

    int ar0 = min(m0 + (tid >> 2), M - 1);
    int ar1 = min(m0 + 64 + (tid >> 2), M - 1);   // used by tid<128 (rows 64..95)
    if (rowmap) { ar0 = rowmap[ar0]; ar1 = rowmap[ar1]; }
    const u16* ag0 = A + (size_t)ar0 * SP + (tid & 3) * 8;
    const u16* ag1 = A + (size_t)ar1 * SP + (tid & 3) * 8;
    const u16* bg0 = Wt + (size_t)(n0 + (tid >> 2)) * SP + (tid & 3) * 8;
    const u16* bg1 = Wt + (size_t)(n0 + 64 + (tid >> 2)) * SP + (tid & 3) * 8;
    const u16* bg2 = Wt + (size_t)(n0 + 128 + (tid >> 2)) * SP + (tid & 3) * 8;

    const float* tp = thr + quad * 8;

    v4f acc[3][5];
#pragma unroll
    for (int nf = 0; nf < 5; nf++) {
        float sv = srow[n0 + wn * 80 + nf * 16 + lm];
#pragma unroll
        for (int mf = 0; mf < 3; mf++)
            acc[mf][nf] = (v4f){sv, sv, sv, sv};
    }

    auto issue = [&](int d, int kt) {
        int ko = kt * 32;
        u16* ad = sm + d * 3072;
        u16* bd = sm + 6144 + d * 5120;
        dma16(ag0 + ko, ad + tid * 8);                       // rows 0..63
        if (tid < 128) dma16(ag1 + ko, ad + (256 + tid) * 8); // rows 64..95
        dma16(bg0 + ko, bd + tid * 8);
        dma16(bg1 + ko, bd + (256 + tid) * 8);
        if (tid < 128) dma16(bg2 + ko, bd + (512 + tid) * 8);
    };

    issue(0, 0);
    for (int kt = 0; kt < SP / 32; kt++) {
        __syncthreads();                      // drains this ktile's DMA
        if (kt + 1 < SP / 32) issue((kt + 1) & 1, kt + 1);
        const u16* as = sm + (kt & 1) * 3072;
        const u16* bs = sm + 6144 + (kt & 1) * 5120;
        float4 ta = *(const float4*)(tp + kt * 32);
        float4 tb = *(const float4*)(tp + kt * 32 + 4);
        v8s b[5], a[3];
#pragma unroll
        for (int nf = 0; nf < 5; nf++)
            b[nf] = *(const v8s*)(bs + (wn * 80 + nf * 16 + lm) * 32 + quad * 8);
#pragma unroll
        for (int mf = 0; mf < 3; mf++) {
            uint4 w = *(const uint4*)(as + (wm * 48 + mf * 16 + lm) * 32 + quad * 8);
            a[mf] = clampA(w, ta, tb);
        }
#pragma unroll
        for (int nf = 0; nf < 5; nf++)
#pragma unroll
            for (int mf = 0; mf < 3; mf++)
                acc[mf][nf] = __builtin_amdgcn_mfma_f32_16x16x32_bf16(a[mf], b[nf], acc[mf][nf], 0, 0, 0);
    }

    __syncthreads();                          // staging reads done -> overlay
#pragma unroll
    for (int mf = 0; mf < 3; mf++)
#pragma unroll
        for (int nf = 0; nf < 5; nf++)
#pragma unroll
            for (int r = 0; r < 4; r++)
                sm[(wm * 48 + mf * 16 + quad * 4 + r) * 168 + wn * 80 + nf * 16 + lm] =
                    f2bf(acc[mf][nf][r]);
    __syncthreads();
#pragma unroll
    for (int i = 0; i < 8; i++) {
        int slot = tid + i * 256;             // 1920 slots = 96 rows x 20 cgroups
        if (slot < 1920) {
            int lr = slot / 20, cg = slot % 20;
            int grow = m0 + lr;
            if (grow < M)
                *(uint4*)(C + (size_t)grow * SP + n0 + cg * 8) =
                    *(const uint4*)(sm + lr * 168 + cg * 8);
        }
    }
}

// ---- aggregate + fused BN stats, flat one-node-per-slot, 4-deep gather -------
__global__ __launch_bounds__(320) void k_aggf(
    const u16* __restrict__ Q, const int* __restrict__ indptr,
    const int* __restrict__ packed, const float* __restrict__ e1,
    const float* __restrict__ e2, u16* __restrict__ P,
    float* __restrict__ colstats, int N) {
    __shared__ float tab[16];
    __shared__ float part[8][328];
    int tid = threadIdx.x;
    int f = tid % 40;
    int slot = tid / 40;
    int n = blockIdx.x * 8 + slot;
    int nn = min(n, N - 1);

    // early independent loads: self row + CSR range (latency overlaps tab setup)
    uint4 sg = *(const uint4*)(Q + (size_t)nn * SP + f * 8);
    int i = indptr[nn];
    int e = indptr[nn + 1];

    if (tid < 16) tab[tid] = (tid < 15) ? e1[tid / 3] + e2[tid % 3] : 0.f;
    __syncthreads();

    float psum[8] = {0, 0, 0, 0, 0, 0, 0, 0};
    float psq[8]  = {0, 0, 0, 0, 0, 0, 0, 0};

    if (n < N) {
        const int PKZ = N | (15 << 17);     // padding row, zero edge weight
        float acc[8];
        unpack8(sg, acc);
        float s = tab[12];                  // self loop: et=4, ed=0 -> code 12
        while (i < e) {
            int pk0 = packed[i];
            int pk1 = (i + 1 < e) ? packed[i + 1] : PKZ;
            int pk2 = (i + 2 < e) ? packed[i + 2] : PKZ;
            int pk3 = (i + 3 < e) ? packed[i + 3] : PKZ;
            uint4 g0 = *(const uint4*)(Q + (size_t)(pk0 & 0x1FFFF) * SP + f * 8);
            uint4 g1 = *(const uint4*)(Q + (size_t)(pk1 & 0x1FFFF) * SP + f * 8);
            uint4 g2 = *(const uint4*)(Q + (size_t)(pk2 & 0x1FFFF) * SP + f * 8);
            uint4 g3 = *(const uint4*)(Q + (size_t)(pk3 & 0x1FFFF) * SP + f * 8);
            float t[8];
            unpack8(g0, t);
#pragma unroll
            for (int q = 0; q < 8; q++) acc[q] += t[q];
            unpack8(g1, t);
#pragma unroll
            for (int q = 0; q < 8; q++) acc[q] += t[q];
            unpack8(g2, t);
#pragma unroll
            for (int q = 0; q < 8; q++) acc[q] += t[q];
            unpack8(g3, t);
#pragma unroll
            for (int q = 0; q < 8; q++) acc[q] += t[q];
            s += tab[pk0 >> 17] + tab[pk1 >> 17] + tab[pk2 >> 17] + tab[pk3 >> 17];
            i += 4;
        }
        u32 o[4];
#pragma unroll
        for (int q = 0; q < 4; q++) {
            float r0 = acc[2 * q] + s;
            float r1 = acc[2 * q + 1] + s;
            psum[2 * q] = r0;      psum[2 * q + 1] = r1;
            psq[2 * q]  = r0 * r0; psq[2 * q + 1]  = r1 * r1;
            o[q] = (u32)f2bf(r0) | ((u32)f2bf(r1) << 16);
        }
        *(uint4*)(P + (size_t)n * SP + f * 8) = make_uint4(o[0], o[1], o[2], o[3]);
    }

    int rep = (blockIdx.x & (NREP - 1)) * 2 * SP;
#pragma unroll
    for (int j = 0; j < 8; j++) part[slot][f * 8 + j] = psum[j];
    __syncthreads();
    {
        float s = 0.f;
#pragma unroll
        for (int k = 0; k < 8; k++) s += part[k][tid];
        atomicAdd(&colstats[rep + tid], s);
    }
    __syncthreads();
#pragma unroll
    for (int j = 0; j < 8; j++) part[slot][f * 8 + j] = psq[j];
    __syncthreads();
    {
        float s = 0.f;
#pragma unroll
        for (int k = 0; k < 8; k++) s += part[k][tid];
        atomicAdd(&colstats[rep + SP + tid], s);
    }
}

// ---- fused: group boundaries from sorted batch + layer-4 BN params ----------
__global__ __launch_bounds__(320) void k_finbounds(
    const int* __restrict__ batch, int* __restrict__ gstart, int N,
    const float* __restrict__ cs, const float* __restrict__ gamma,
    const float* __restrict__ beta, float* __restrict__ sc, float* __restrict__ sh) {
    int t = threadIdx.x;
    int n = blockIdx.x * 320 + t;
    if (n <= N) {
        int bcur = (n < N) ? batch[n] : NGRP;
        int bprev = (n > 0) ? batch[n - 1] : -1;
        for (int g = bprev + 1; g <= bcur; g++) gstart[g] = n;
    }
    if (blockIdx.x == 0 && t < SP) {
        float s1 = 0.f, s2 = 0.f;
        for (int r = 0; r < NREP; r++) {
            s1 += cs[r * 2 * SP + t];
            s2 += cs[r * 2 * SP + SP + t];
        }
        if (t < EMB) {
            float inv = 1.f / (float)N;
            float mean = s1 * inv;
            float var = s2 * inv - mean * mean;
            float rstd = rsqrtf(fmaxf(var, 0.f) + 1e-5f);
            float s = gamma[t] * rstd;
            sc[t] = s;
            sh[t] = beta[t] - mean * s;
        } else {
            sc[t] = 0.f; sh[t] = 0.f;
        }
    }
}

// ------------------- pool (BN layer4 fused, no relu), 8 groups/block ----------
__global__ __launch_bounds__(320) void k_pool(
    const u16* __restrict__ P, const float* __restrict__ sc,
    const float* __restrict__ sh, const int* __restrict__ gstart,
    float* __restrict__ hg) {
    int tid = threadIdx.x;
    int g = blockIdx.x * 8 + tid / 40;
    int f = tid % 40;
    int r0 = gstart[g], r1 = gstart[g + 1];
    int cnt = r1 - r0;
    float acc[8] = {0, 0, 0, 0, 0, 0, 0, 0};
    for (int r = r0; r < r1; r++) {
        float t[8];
        unpack8(*(const uint4*)(P + (size_t)r * SP + f * 8), t);
#pragma unroll
        for (int j = 0; j < 8; j++) acc[j] += t[j];
    }
    float inv = 1.f / (float)max(cnt, 1);
#pragma unroll
    for (int j = 0; j < 8; j++) {
        int c = f * 8 + j;
        if (c < EMB)
            hg[(size_t)g * EMB + c] = (acc[j] * sc[c] + (float)cnt * sh[c]) * inv;
    }
}

// ------------------- hf = hg @ feat_W + feat_b (32 groups/block) --------------
__global__ __launch_bounds__(256) void k_feat(const float* __restrict__ hg,
                                              const float* __restrict__ fW,
                                              const float* __restrict__ fb,
                                              float* __restrict__ hf) {
    __shared__ float hgs[32 * EMB];
    int g0 = blockIdx.x * 32;
    int tid = threadIdx.x;
    for (int i = tid; i < 32 * EMB; i += 256) {
        int gi = i / EMB, c = i % EMB;
        hgs[i] = hg[(size_t)(g0 + gi) * EMB + c];
    }
    __syncthreads();
    float acc[32];
    float fbv = fb[tid];
#pragma unroll
    for (int gi = 0; gi < 32; gi++) acc[gi] = fbv;
    for (int k = 0; k < EMB; k++) {
        float w = fW[(size_t)k * FEAT + tid];
#pragma unroll
        for (int gi = 0; gi < 32; gi++) acc[gi] += hgs[gi * EMB + k] * w;
    }
#pragma unroll
    for (int gi = 0; gi < 32; gi++) hf[(size_t)(g0 + gi) * FEAT + tid] = acc[gi];
}

// ------------------- head: pred = softplus(hf@W1+b1)@W2+b2 (16 groups/block) --
__global__ __launch_bounds__(128) void k_head(const float* __restrict__ hf,
                                              const float* __restrict__ W1,
                                              const float* __restrict__ b1,
                                              const float* __restrict__ W2,
                                              const float* __restrict__ b2,
                                              float* __restrict__ pred) {
    __shared__ float hfs[16 * FEAT];
    __shared__ float sred[2][16][2];
    int g0 = blockIdx.x * 16;
    int tid = threadIdx.x;
    for (int i = tid; i < 16 * FEAT; i += 128) {
        int gi = i >> 8, k = i & 255;
        hfs[i] = hf[(size_t)(g0 + gi) * FEAT + k];
    }
    __syncthreads();
    float acc[16];
    float b1v = b1[tid];
#pragma unroll
    for (int gi = 0; gi < 16; gi++) acc[gi] = b1v;
    for (int k = 0; k < FEAT; k++) {
        float w = W1[(size_t)k * 128 + tid];
#pragma unroll
        for (int gi = 0; gi < 16; gi++) acc[gi] += hfs[gi * FEAT + k] * w;
    }
    float w20 = W2[tid * 2], w21 = W2[tid * 2 + 1];
    int wv = tid >> 6;
#pragma unroll
    for (int gi = 0; gi < 16; gi++) {
        float x = acc[gi];
        float t = fmaxf(x, 0.f) + log1pf(expf(-fabsf(x)));
        float p0 = t * w20, p1 = t * w21;
#pragma unroll
        for (int off = 32; off > 0; off >>= 1) {
            p0 += __shfl_down(p0, off);
            p1 += __shfl_down(p1, off);
        }
        if ((tid & 63) == 0) { sred[wv][gi][0] = p0; sred[wv][gi][1] = p1; }
    }
    __syncthreads();
    if (tid < 32) {
        int gi = tid >> 1, o = tid & 1;
        pred[(size_t)(g0 + gi) * 2 + o] = sred[0][gi][o] + sred[1][gi][o] + b2[o];
    }
}

// ------------------- launch -------------------
extern "C" void kernel_launch(void* const* d_in, const int* in_sizes, int n_in,
                              void* d_out, int out_size, void* d_ws, size_t ws_size,
                              hipStream_t stream) {
    const int* atom_type = (const int*)d_in[0];
    const int* chir      = (const int*)d_in[1];
    const int* eidx      = (const int*)d_in[2];
    const int* etype     = (const int*)d_in[3];
    const int* edir      = (const int*)d_in[4];
    const int* batch     = (const int*)d_in[5];
    const float* emb1    = (const float*)d_in[6];
    const float* emb2    = (const float*)d_in[7];
    const float* W       = (const float*)d_in[8];
    const float* ee1     = (const float*)d_in[10];
    const float* ee2     = (const float*)d_in[11];
    const float* gamma   = (const float*)d_in[12];
    const float* beta    = (const float*)d_in[13];
    const float* featW   = (const float*)d_in[14];
    const float* featb   = (const float*)d_in[15];
    const float* hW1     = (const float*)d_in[16];
    const float* hb1     = (const float*)d_in[17];
    const float* hW2     = (const float*)d_in[18];
    const float* hb2     = (const float*)d_in[19];

    int N = in_sizes[0];
    int E = in_sizes[2] / 2;
    const int* erow = eidx;
    const int* ecol = eidx + E;

    size_t off = 0;
    char* base = (char*)d_ws;
    auto carve = [&](size_t bytes) -> void* {
        void* p = base + off;
        off += (bytes + 255) & ~(size_t)255;
        return p;
    };
    u16*   P        = (u16*)  carve((size_t)(N + 1) * SP * 2);
    u16*   Q        = (u16*)  carve((size_t)(N + 1) * SP * 2);
    u16*   Wt       = (u16*)  carve((size_t)SP * SP * 2);
    u16*   comb     = (u16*)  carve((size_t)NCOMB * SP * 2);
    int*   c9map    = (int*)  carve((size_t)N * 4);
    int*   deg      = (int*)  carve((size_t)N * 4);
    int*   cursor   = (int*)  carve((size_t)N * 4);
    int*   indptr   = (int*)  carve((size_t)(N + 1) * 4);
    int*   packed   = (int*)  carve((size_t)(E + 8) * 4);
    int*   bsum     = (int*)  carve(1024 * 4);
    float* cs0      = (float*)carve((size_t)CSB * 4);   // colstats bank 0
    float* cs1      = (float*)carve((size_t)CSB * 4);   // colstats bank 1
    float* scale_bn = (float*)carve(SP * 4);
    float* shift_bn = (float*)carve(SP * 4);
    float* thr_bn   = (float*)carve(SP * 4);
    float* srow     = (float*)carve(SP * 4);
    int*   gstart   = (int*)  carve((size_t)(NGRP + 1) * 4);
    float* hg       = (float*)carve((size_t)NGRP * EMB * 4);

    float* hf   = (float*)d_out;
    float* pred = (float*)d_out + (size_t)NGRP * FEAT;

    int eb = (E + 255) / 256;
    int NB = (N + 1023) / 1024;
    k_prep_n<<<(N + 255) / 256, 256, 0, stream>>>(atom_type, chir, c9map, deg, cursor,
                                                  Q, N);
    k_cntcomb<<<eb, 256, 0, stream>>>(ecol, deg, E, emb1, emb2, comb);
    k_bsum<<<NB, 256, 0, stream>>>(deg, bsum, N);
    k_indptr<<<NB, 256, 0, stream>>>(deg, bsum, indptr, N, NB);
    k_fill<<<eb, 256, 0, stream>>>(erow, ecol, etype, edir, indptr, cursor, packed, E);

    dim3 ggrid(2, (N + MT - 1) / MT);   // x = n-tile, y = m-tile
    int ab = (N + 7) / 8;
    float* banks[2] = {cs0, cs1};
    for (int l = 0; l < 5; l++) {
        float* wb = banks[l & 1];          // bank aggf(l) writes (wprep zeros it)
        float* rb = banks[(l + 1) & 1];    // bank wprep(l) reads (aggf(l-1)'s)
        k_wprep<<<SP, 320, 0, stream>>>(W + (size_t)l * EMB * EMB, rb,
                                        gamma + l * EMB - EMB, beta + l * EMB - EMB,
                                        l == 0 ? 1 : 0, N, Wt, srow, thr_bn, wb);
        if (l == 0)
            k_gemm<<<ggrid, 256, 0, stream>>>(comb, Wt, thr_bn, srow, Q, N, c9map);
        else
            k_gemm<<<ggrid, 256, 0, stream>>>(P, Wt, thr_bn, srow, Q, N, nullptr);
        k_aggf<<<ab, 320, 0, stream>>>(Q, indptr, packed, ee1 + l * 5, ee2 + l * 3, P,
                                       wb, N);
    }

    // layer-4 BN params (aggf(4) wrote bank 0) + group bounds, fused
    k_finbounds<<<(N + 320) / 320, 320, 0, stream>>>(batch, gstart, N, banks[0],
                                                     gamma + 4 * EMB, beta + 4 * EMB,
                                                     scale_bn, shift_bn);
    k_pool<<<NGRP / 8, 320, 0, stream>>>(P, scale_bn, shift_bn, gstart, hg);
    k_feat<<<NGRP / 32, 256, 0, stream>>>(hg, featW, featb, hf);
    k_head<<<NGRP / 16, 128, 0, stream>>>(hf, hW1, hb1, hW2, hb2, pred);
}

// Round 8
// 667.537 us; speedup vs baseline: 1.0455x; 1.0455x over previous
//
#include <hip/hip_runtime.h>
#include <math.h>

typedef unsigned short u16;
typedef unsigned int u32;
typedef short v8s __attribute__((ext_vector_type(8)));
typedef float v4f __attribute__((ext_vector_type(4)));

#define EMB 300
#define SP 320            // padded feature stride (bf16 elems)
#define NGRP 4096
#define FEAT 256
#define MT 96
#define NT 160
#define NCOMB 357         // 119 atom types x 3 chirality
#define NREP 32           // colstats replicas (atomic spread)
#define CSB (NREP * 2 * SP)   // floats per colstats bank

__device__ __forceinline__ u16 f2bf(float x) {
    u32 u = __float_as_uint(x);
    u += 0x7FFFu + ((u >> 16) & 1u);
    return (u16)(u >> 16);
}
__device__ __forceinline__ float bf2f(u16 h) {
    return __uint_as_float((u32)h << 16);
}
__device__ __forceinline__ void unpack8(uint4 w, float* o) {
    const u32* p = &w.x;
#pragma unroll
    for (int q = 0; q < 4; q++) {
        o[2 * q]     = __uint_as_float(p[q] << 16);
        o[2 * q + 1] = __uint_as_float(p[q] & 0xFFFF0000u);
    }
}
// clamp 8 packed bf16 against per-col bf16-exact thresholds (lossless repack)
// perm repack: dst = (lo>>16) | (hi & 0xFFFF0000)
__device__ __forceinline__ v8s clampA(uint4 w, float4 ta, float4 tb) {
    const u32* p = &w.x;
    float t[8] = {ta.x, ta.y, ta.z, ta.w, tb.x, tb.y, tb.z, tb.w};
    u32 o[4];
#pragma unroll
    for (int q = 0; q < 4; q++) {
        float lo = __uint_as_float(p[q] << 16);
        float hi = __uint_as_float(p[q] & 0xFFFF0000u);
        lo = fmaxf(lo, t[2 * q]);
        hi = fmaxf(hi, t[2 * q + 1]);
        o[q] = __builtin_amdgcn_perm(__float_as_uint(hi), __float_as_uint(lo),
                                     0x07060302u);
    }
    uint4 r = make_uint4(o[0], o[1], o[2], o[3]);
    return *(v8s*)&r;
}
// async global->LDS DMA, 16B per lane (dest = wave-uniform base + lane*16)
__device__ __forceinline__ void dma16(const u16* g, u16* l) {
    __builtin_amdgcn_global_load_lds(
        (const __attribute__((address_space(1))) unsigned int*)g,
        (__attribute__((address_space(3))) unsigned int*)l, 16, 0, 0);
}

// ---------- per-node prep: c9 map + zero deg/cursor + Q pad row --------------
__global__ void k_prep_n(const int* __restrict__ at, const int* __restrict__ ch,
                         int* __restrict__ c9, int* __restrict__ deg,
                         int* __restrict__ cursor, u16* __restrict__ Q, int N) {
    int n = blockIdx.x * blockDim.x + threadIdx.x;
    if (n < N) {
        c9[n] = at[n] * 3 + ch[n];
        deg[n] = 0;
        cursor[n] = 0;
    }
    // zero padding row Q[N] (gather target for out-of-range unroll slots)
    if (n < SP / 2) ((u32*)(Q + (size_t)N * SP))[n] = 0u;
}

// ---------- fused: edge count (CSR deg) + comb table build -------------------
__global__ void k_cntcomb(const int* __restrict__ col, int* __restrict__ deg, int E,
                          const float* __restrict__ e1, const float* __restrict__ e2,
                          u16* __restrict__ comb) {
    int i = blockIdx.x * blockDim.x + threadIdx.x;
    if (i < E) atomicAdd(&deg[col[i]], 1);
    if (i < NCOMB * 40) {
        int row = i / 40, f = i % 40;
        int at = row / 3, ch = row % 3;
        u32 o[4];
#pragma unroll
        for (int q = 0; q < 4; q++) {
            int c0 = f * 8 + q * 2;
            float x0 = 0.f, x1 = 0.f;
            if (c0 < EMB)     x0 = e1[(size_t)at * EMB + c0] + e2[(size_t)ch * EMB + c0];
            if (c0 + 1 < EMB) x1 = e1[(size_t)at * EMB + c0 + 1] + e2[(size_t)ch * EMB + c0 + 1];
            o[q] = (u32)f2bf(x0) | ((u32)f2bf(x1) << 16);
        }
        *(uint4*)(comb + (size_t)row * SP + f * 8) = make_uint4(o[0], o[1], o[2], o[3]);
    }
}

__global__ __launch_bounds__(256) void k_bsum(const int* __restrict__ deg,
                                              int* __restrict__ bsum, int N) {
    int base = blockIdx.x * 1024 + threadIdx.x * 4;
    int s = 0;
    if (base + 3 < N) {
        int4 v = *(const int4*)(deg + base);
        s = v.x + v.y + v.z + v.w;
    } else {
        for (int j = 0; j < 4; j++) if (base + j < N) s += deg[base + j];
    }
    __shared__ int red[256];
    red[threadIdx.x] = s;
    __syncthreads();
    for (int off = 128; off > 0; off >>= 1) {
        if (threadIdx.x < off) red[threadIdx.x] += red[threadIdx.x + off];
        __syncthreads();
    }
    if (threadIdx.x == 0) bsum[blockIdx.x] = red[0];
}

// indptr with block-offset scan fused in (each block redundantly scans bsum)
__global__ __launch_bounds__(256) void k_indptr(const int* __restrict__ deg,
                                                const int* __restrict__ bsum,
                                                int* __restrict__ indptr, int N, int NB) {
    __shared__ int bs[128];
    __shared__ int sh[256];
    int b = blockIdx.x, t = threadIdx.x;
    if (t < 128) bs[t] = (t < NB) ? bsum[t] : 0;
    __syncthreads();
    for (int off = 1; off < 128; off <<= 1) {
        int add = (t < 128 && t >= off) ? bs[t - off] : 0;
        __syncthreads();
        if (t < 128) bs[t] += add;
        __syncthreads();
    }
    int boffb = (b > 0) ? bs[b - 1] : 0;

    int base = b * 1024 + t * 4;
    int v[4] = {0, 0, 0, 0};
    if (base + 3 < N) {
        int4 w = *(const int4*)(deg + base);
        v[0] = w.x; v[1] = w.y; v[2] = w.z; v[3] = w.w;
    } else {
        for (int j = 0; j < 4; j++) if (base + j < N) v[j] = deg[base + j];
    }
    int tsum = v[0] + v[1] + v[2] + v[3];
    sh[t] = tsum;
    __syncthreads();
    for (int off = 1; off < 256; off <<= 1) {
        int add = (t >= off) ? sh[t - off] : 0;
        __syncthreads();
        sh[t] += add;
        __syncthreads();
    }
    int run = boffb + sh[t] - tsum;
    for (int j = 0; j < 4; j++) {
        run += v[j];
        if (base + j < N) indptr[base + j + 1] = run;
    }
    if (b == 0 && t == 0) indptr[0] = 0;
}

__global__ void k_fill(const int* __restrict__ row, const int* __restrict__ col,
                       const int* __restrict__ et, const int* __restrict__ ed,
                       const int* __restrict__ indptr, int* __restrict__ cursor,
                       int* __restrict__ packed, int E) {
    int e = blockIdx.x * blockDim.x + threadIdx.x;
    if (e >= E) return;
    int c = col[e];
    int pos = indptr[c] + atomicAdd(&cursor[c], 1);
    packed[pos] = row[e] | ((et[e] * 3 + ed[e]) << 17);
}

// ---- fused W prep: BN-finalize + Wt + srow + thr + zero next colstats bank --
__global__ __launch_bounds__(320) void k_wprep(
    const float* __restrict__ Wl, const float* __restrict__ cs,
    const float* __restrict__ gamma, const float* __restrict__ beta,
    int ident, int N, u16* __restrict__ Wt, float* __restrict__ srow,
    float* __restrict__ thr, float* __restrict__ wb) {
    __shared__ float wred[5];
    int n = blockIdx.x;
    int k = threadIdx.x;

    // zero the bank aggf(this layer) will write (blocks 0..63 cover CSB)
    int zi = n * 320 + k;
    if (zi < CSB) wb[zi] = 0.f;

    float scv, shv, thv;
    if (ident) {
        scv = (k < EMB) ? 1.f : 0.f;
        shv = 0.f;
        thv = -__builtin_inff();
    } else if (k < EMB) {
        float s1 = 0.f, s2 = 0.f;
        for (int r = 0; r < NREP; r++) {
            s1 += cs[r * 2 * SP + k];
            s2 += cs[r * 2 * SP + SP + k];
        }
        float inv = 1.f / (float)N;
        float mean = s1 * inv;
        float var = s2 * inv - mean * mean;
        float rstd = rsqrtf(fmaxf(var, 0.f) + 1e-5f);
        scv = gamma[k] * rstd;
        shv = beta[k] - mean * scv;
        thv = bf2f(f2bf(-shv / scv));
    } else {
        scv = 0.f; shv = 0.f; thv = -__builtin_inff();
    }
    if (n == 0) thr[k] = thv;

    float w = 0.f;
    if (n < EMB && k < EMB) w = Wl[(size_t)k * EMB + n];
    Wt[(size_t)n * SP + k] = f2bf(w * scv);
    float s = (k < EMB) ? shv * w : 0.f;
#pragma unroll
    for (int o2 = 32; o2 > 0; o2 >>= 1) s += __shfl_down(s, o2);
    if ((k & 63) == 0) wred[k >> 6] = s;
    __syncthreads();
    if (k == 0) {
        float t = wred[0] + wred[1] + wred[2] + wred[3] + wred[4];
        srow[n] = (n < EMB) ? t : 0.f;
    }
}

// ------------------- GEMM: Q = max(A[rowmap], thr) @ Wt + srow  ---------------
// v6: R2 schedule (BK=32, all-DMA double-buffer, clamp at read) with MT=96:
// LDS staging = A 2x6KB + B 2x10KB = exactly 32KB -> 5 blocks/CU (was 4).
// Per-wave fragments 3x5; single-pass epilogue (96x168 u16 = 31.5KB overlay).
__global__ __launch_bounds__(256) void k_gemm(
    const u16* __restrict__ A, const u16* __restrict__ Wt,
    const float* __restrict__ thr, const float* __restrict__ srow,
    u16* __restrict__ C, int M, const int* __restrict__ rowmap) {
    __shared__ __align__(16) u16 sm[16384];   // A 2x3072 | B 2x5120 ; epi 96x168

    int m0 = blockIdx.y * MT;
    int n0 = blockIdx.x * NT;
    int tid = threadIdx.x;
    int wave = tid >> 6, lane = tid & 63;
    int wm = wave >> 1, wn = wave & 1;
    int lm = lane & 15, quad = lane >> 4;

    int ar0 = min(m0 + (tid >> 2), M - 1);
    int ar1 = min(m0 + 64 + (tid >> 2), M - 1);   // used by tid<128 (rows 64..95)
    if (rowmap) { ar0 = rowmap[ar0]; ar1 = rowmap[ar1]; }
    const u16* ag0 = A + (size_t)ar0 * SP + (tid & 3) * 8;
    const u16* ag1 = A + (size_t)ar1 * SP + (tid & 3) * 8;
    const u16* bg0 = Wt + (size_t)(n0 + (tid >> 2)) * SP + (tid & 3) * 8;
    const u16* bg1 = Wt + (size_t)(n0 + 64 + (tid >> 2)) * SP + (tid & 3) * 8;
    const u16* bg2 = Wt + (size_t)(n0 + 128 + (tid >> 2)) * SP + (tid & 3) * 8;

    const float* tp = thr + quad * 8;

    v4f acc[3][5];
#pragma unroll
    for (int nf = 0; nf < 5; nf++) {
        float sv = srow[n0 + wn * 80 + nf * 16 + lm];
#pragma unroll
        for (int mf = 0; mf < 3; mf++)
            acc[mf][nf] = (v4f){sv, sv, sv, sv};
    }

    auto issue = [&](int d, int kt) {
        int ko = kt * 32;
        u16* ad = sm + d * 3072;
        u16* bd = sm + 6144 + d * 5120;
        dma16(ag0 + ko, ad + tid * 8);                       // rows 0..63
        if (tid < 128) dma16(ag1 + ko, ad + (256 + tid) * 8); // rows 64..95
        dma16(bg0 + ko, bd + tid * 8);
        dma16(bg1 + ko, bd + (256 + tid) * 8);
        if (tid < 128) dma16(bg2 + ko, bd + (512 + tid) * 8);
    };

    issue(0, 0);
    for (int kt = 0; kt < SP / 32; kt++) {
        __syncthreads();                      // drains this ktile's DMA
        if (kt + 1 < SP / 32) issue((kt + 1) & 1, kt + 1);
        const u16* as = sm + (kt & 1) * 3072;
        const u16* bs = sm + 6144 + (kt & 1) * 5120;
        float4 ta = *(const float4*)(tp + kt * 32);
        float4 tb = *(const float4*)(tp + kt * 32 + 4);
        v8s b[5], a[3];
#pragma unroll
        for (int nf = 0; nf < 5; nf++)
            b[nf] = *(const v8s*)(bs + (wn * 80 + nf * 16 + lm) * 32 + quad * 8);
#pragma unroll
        for (int mf = 0; mf < 3; mf++) {
            uint4 w = *(const uint4*)(as + (wm * 48 + mf * 16 + lm) * 32 + quad * 8);
            a[mf] = clampA(w, ta, tb);
        }
#pragma unroll
        for (int nf = 0; nf < 5; nf++)
#pragma unroll
            for (int mf = 0; mf < 3; mf++)
                acc[mf][nf] = __builtin_amdgcn_mfma_f32_16x16x32_bf16(a[mf], b[nf], acc[mf][nf], 0, 0, 0);
    }

    __syncthreads();                          // staging reads done -> overlay
#pragma unroll
    for (int mf = 0; mf < 3; mf++)
#pragma unroll
        for (int nf = 0; nf < 5; nf++)
#pragma unroll
            for (int r = 0; r < 4; r++)
                sm[(wm * 48 + mf * 16 + quad * 4 + r) * 168 + wn * 80 + nf * 16 + lm] =
                    f2bf(acc[mf][nf][r]);
    __syncthreads();
#pragma unroll
    for (int i = 0; i < 8; i++) {
        int slot = tid + i * 256;             // 1920 slots = 96 rows x 20 cgroups
        if (slot < 1920) {
            int lr = slot / 20, cg = slot % 20;
            int grow = m0 + lr;
            if (grow < M)
                *(uint4*)(C + (size_t)grow * SP + n0 + cg * 8) =
                    *(const uint4*)(sm + lr * 168 + cg * 8);
        }
    }
}

// ---- aggregate + fused BN stats, flat one-node-per-slot, 4-deep gather -------
__global__ __launch_bounds__(320) void k_aggf(
    const u16* __restrict__ Q, const int* __restrict__ indptr,
    const int* __restrict__ packed, const float* __restrict__ e1,
    const float* __restrict__ e2, u16* __restrict__ P,
    float* __restrict__ colstats, int N) {
    __shared__ float tab[16];
    __shared__ float part[8][328];
    int tid = threadIdx.x;
    int f = tid % 40;
    int slot = tid / 40;
    int n = blockIdx.x * 8 + slot;
    int nn = min(n, N - 1);

    // early independent loads: self row + CSR range (latency overlaps tab setup)
    uint4 sg = *(const uint4*)(Q + (size_t)nn * SP + f * 8);
    int i = indptr[nn];
    int e = indptr[nn + 1];

    if (tid < 16) tab[tid] = (tid < 15) ? e1[tid / 3] + e2[tid % 3] : 0.f;
    __syncthreads();

    float psum[8] = {0, 0, 0, 0, 0, 0, 0, 0};
    float psq[8]  = {0, 0, 0, 0, 0, 0, 0, 0};

    if (n < N) {
        const int PKZ = N | (15 << 17);     // padding row, zero edge weight
        float acc[8];
        unpack8(sg, acc);
        float s = tab[12];                  // self loop: et=4, ed=0 -> code 12
        while (i < e) {
            int pk0 = packed[i];
            int pk1 = (i + 1 < e) ? packed[i + 1] : PKZ;
            int pk2 = (i + 2 < e) ? packed[i + 2] : PKZ;
            int pk3 = (i + 3 < e) ? packed[i + 3] : PKZ;
            uint4 g0 = *(const uint4*)(Q + (size_t)(pk0 & 0x1FFFF) * SP + f * 8);
            uint4 g1 = *(const uint4*)(Q + (size_t)(pk1 & 0x1FFFF) * SP + f * 8);
            uint4 g2 = *(const uint4*)(Q + (size_t)(pk2 & 0x1FFFF) * SP + f * 8);
            uint4 g3 = *(const uint4*)(Q + (size_t)(pk3 & 0x1FFFF) * SP + f * 8);
            float t[8];
            unpack8(g0, t);
#pragma unroll
            for (int q = 0; q < 8; q++) acc[q] += t[q];
            unpack8(g1, t);
#pragma unroll
            for (int q = 0; q < 8; q++) acc[q] += t[q];
            unpack8(g2, t);
#pragma unroll
            for (int q = 0; q < 8; q++) acc[q] += t[q];
            unpack8(g3, t);
#pragma unroll
            for (int q = 0; q < 8; q++) acc[q] += t[q];
            s += tab[pk0 >> 17] + tab[pk1 >> 17] + tab[pk2 >> 17] + tab[pk3 >> 17];
            i += 4;
        }
        u32 o[4];
#pragma unroll
        for (int q = 0; q < 4; q++) {
            float r0 = acc[2 * q] + s;
            float r1 = acc[2 * q + 1] + s;
            psum[2 * q] = r0;      psum[2 * q + 1] = r1;
            psq[2 * q]  = r0 * r0; psq[2 * q + 1]  = r1 * r1;
            o[q] = (u32)f2bf(r0) | ((u32)f2bf(r1) << 16);
        }
        *(uint4*)(P + (size_t)n * SP + f * 8) = make_uint4(o[0], o[1], o[2], o[3]);
    }

    int rep = (blockIdx.x & (NREP - 1)) * 2 * SP;
#pragma unroll
    for (int j = 0; j < 8; j++) part[slot][f * 8 + j] = psum[j];
    __syncthreads();
    {
        float s = 0.f;
#pragma unroll
        for (int k = 0; k < 8; k++) s += part[k][tid];
        atomicAdd(&colstats[rep + tid], s);
    }
    __syncthreads();
#pragma unroll
    for (int j = 0; j < 8; j++) part[slot][f * 8 + j] = psq[j];
    __syncthreads();
    {
        float s = 0.f;
#pragma unroll
        for (int k = 0; k < 8; k++) s += part[k][tid];
        atomicAdd(&colstats[rep + SP + tid], s);
    }
}

// ---- fused: group boundaries from sorted batch + layer-4 BN params ----------
__global__ __launch_bounds__(320) void k_finbounds(
    const int* __restrict__ batch, int* __restrict__ gstart, int N,
    const float* __restrict__ cs, const float* __restrict__ gamma,
    const float* __restrict__ beta, float* __restrict__ sc, float* __restrict__ sh) {
    int t = threadIdx.x;
    int n = blockIdx.x * 320 + t;
    if (n <= N) {
        int bcur = (n < N) ? batch[n] : NGRP;
        int bprev = (n > 0) ? batch[n - 1] : -1;
        for (int g = bprev + 1; g <= bcur; g++) gstart[g] = n;
    }
    if (blockIdx.x == 0 && t < SP) {
        float s1 = 0.f, s2 = 0.f;
        for (int r = 0; r < NREP; r++) {
            s1 += cs[r * 2 * SP + t];
            s2 += cs[r * 2 * SP + SP + t];
        }
        if (t < EMB) {
            float inv = 1.f / (float)N;
            float mean = s1 * inv;
            float var = s2 * inv - mean * mean;
            float rstd = rsqrtf(fmaxf(var, 0.f) + 1e-5f);
            float s = gamma[t] * rstd;
            sc[t] = s;
            sh[t] = beta[t] - mean * s;
        } else {
            sc[t] = 0.f; sh[t] = 0.f;
        }
    }
}

// ------------------- pool (BN layer4 fused, no relu), 8 groups/block ----------
__global__ __launch_bounds__(320) void k_pool(
    const u16* __restrict__ P, const float* __restrict__ sc,
    const float* __restrict__ sh, const int* __restrict__ gstart,
    float* __restrict__ hg) {
    int tid = threadIdx.x;
    int g = blockIdx.x * 8 + tid / 40;
    int f = tid % 40;
    int r0 = gstart[g], r1 = gstart[g + 1];
    int cnt = r1 - r0;
    float acc[8] = {0, 0, 0, 0, 0, 0, 0, 0};
    for (int r = r0; r < r1; r++) {
        float t[8];
        unpack8(*(const uint4*)(P + (size_t)r * SP + f * 8), t);
#pragma unroll
        for (int j = 0; j < 8; j++) acc[j] += t[j];
    }
    float inv = 1.f / (float)max(cnt, 1);
#pragma unroll
    for (int j = 0; j < 8; j++) {
        int c = f * 8 + j;
        if (c < EMB)
            hg[(size_t)g * EMB + c] = (acc[j] * sc[c] + (float)cnt * sh[c]) * inv;
    }
}

// ------------------- hf = hg @ feat_W + feat_b -------------------
__global__ __launch_bounds__(256) void k_feat(const float* __restrict__ hg,
                                              const float* __restrict__ fW,
                                              const float* __restrict__ fb,
                                              float* __restrict__ hf) {
    __shared__ float hgs[16 * EMB];
    int g0 = blockIdx.x * 16;
    int tid = threadIdx.x;
    for (int i = tid; i < 16 * EMB; i += 256) {
        int gi = i / EMB, c = i % EMB;
        hgs[i] = hg[(size_t)(g0 + gi) * EMB + c];
    }
    __syncthreads();
    float acc[16];
    float fbv = fb[tid];
#pragma unroll
    for (int gi = 0; gi < 16; gi++) acc[gi] = fbv;
    for (int k = 0; k < EMB; k++) {
        float w = fW[(size_t)k * FEAT + tid];
#pragma unroll
        for (int gi = 0; gi < 16; gi++) acc[gi] += hgs[gi * EMB + k] * w;
    }
#pragma unroll
    for (int gi = 0; gi < 16; gi++) hf[(size_t)(g0 + gi) * FEAT + tid] = acc[gi];
}

// ------------------- head: pred = softplus(hf@W1+b1)@W2+b2 -------------------
__global__ __launch_bounds__(128) void k_head(const float* __restrict__ hf,
                                              const float* __restrict__ W1,
                                              const float* __restrict__ b1,
                                              const float* __restrict__ W2,
                                              const float* __restrict__ b2,
                                              float* __restrict__ pred) {
    __shared__ float hfs[8 * FEAT];
    __shared__ float sred[2][8][2];
    int g0 = blockIdx.x * 8;
    int tid = threadIdx.x;
    for (int i = tid; i < 8 * FEAT; i += 128) {
        int gi = i >> 8, k = i & 255;
        hfs[i] = hf[(size_t)(g0 + gi) * FEAT + k];
    }
    __syncthreads();
    float acc[8];
    float b1v = b1[tid];
#pragma unroll
    for (int gi = 0; gi < 8; gi++) acc[gi] = b1v;
    for (int k = 0; k < FEAT; k++) {
        float w = W1[(size_t)k * 128 + tid];
#pragma unroll
        for (int gi = 0; gi < 8; gi++) acc[gi] += hfs[gi * FEAT + k] * w;
    }
    float w20 = W2[tid * 2], w21 = W2[tid * 2 + 1];
    int wv = tid >> 6;
#pragma unroll
    for (int gi = 0; gi < 8; gi++) {
        float x = acc[gi];
        float t = fmaxf(x, 0.f) + log1pf(expf(-fabsf(x)));
        float p0 = t * w20, p1 = t * w21;
#pragma unroll
        for (int off = 32; off > 0; off >>= 1) {
            p0 += __shfl_down(p0, off);
            p1 += __shfl_down(p1, off);
        }
        if ((tid & 63) == 0) { sred[wv][gi][0] = p0; sred[wv][gi][1] = p1; }
    }
    __syncthreads();
    if (tid < 16) {
        int gi = tid >> 1, o = tid & 1;
        pred[(size_t)(g0 + gi) * 2 + o] = sred[0][gi][o] + sred[1][gi][o] + b2[o];
    }
}

// ------------------- launch -------------------
extern "C" void kernel_launch(void* const* d_in, const int* in_sizes, int n_in,
                              void* d_out, int out_size, void* d_ws, size_t ws_size,
                              hipStream_t stream) {
    const int* atom_type = (const int*)d_in[0];
    const int* chir      = (const int*)d_in[1];
    const int* eidx      = (const int*)d_in[2];
    const int* etype     = (const int*)d_in[3];
    const int* edir      = (const int*)d_in[4];
    const int* batch     = (const int*)d_in[5];
    const float* emb1    = (const float*)d_in[6];
    const float* emb2    = (const float*)d_in[7];
    const float* W       = (const float*)d_in[8];
    const float* ee1     = (const float*)d_in[10];
    const float* ee2     = (const float*)d_in[11];
    const float* gamma   = (const float*)d_in[12];
    const float* beta    = (const float*)d_in[13];
    const float* featW   = (const float*)d_in[14];
    const float* featb   = (const float*)d_in[15];
    const float* hW1     = (const float*)d_in[16];
    const float* hb1     = (const float*)d_in[17];
    const float* hW2     = (const float*)d_in[18];
    const float* hb2     = (const float*)d_in[19];

    int N = in_sizes[0];
    int E = in_sizes[2] / 2;
    const int* erow = eidx;
    const int* ecol = eidx + E;

    size_t off = 0;
    char* base = (char*)d_ws;
    auto carve = [&](size_t bytes) -> void* {
        void* p = base + off;
        off += (bytes + 255) & ~(size_t)255;
        return p;
    };
    u16*   P        = (u16*)  carve((size_t)(N + 1) * SP * 2);
    u16*   Q        = (u16*)  carve((size_t)(N + 1) * SP * 2);
    u16*   Wt       = (u16*)  carve((size_t)SP * SP * 2);
    u16*   comb     = (u16*)  carve((size_t)NCOMB * SP * 2);
    int*   c9map    = (int*)  carve((size_t)N * 4);
    int*   deg      = (int*)  carve((size_t)N * 4);
    int*   cursor   = (int*)  carve((size_t)N * 4);
    int*   indptr   = (int*)  carve((size_t)(N + 1) * 4);
    int*   packed   = (int*)  carve((size_t)(E + 8) * 4);
    int*   bsum     = (int*)  carve(1024 * 4);
    float* cs0      = (float*)carve((size_t)CSB * 4);   // colstats bank 0
    float* cs1      = (float*)carve((size_t)CSB * 4);   // colstats bank 1
    float* scale_bn = (float*)carve(SP * 4);
    float* shift_bn = (float*)carve(SP * 4);
    float* thr_bn   = (float*)carve(SP * 4);
    float* srow     = (float*)carve(SP * 4);
    int*   gstart   = (int*)  carve((size_t)(NGRP + 1) * 4);
    float* hg       = (float*)carve((size_t)NGRP * EMB * 4);

    float* hf   = (float*)d_out;
    float* pred = (float*)d_out + (size_t)NGRP * FEAT;

    int eb = (E + 255) / 256;
    int NB = (N + 1023) / 1024;
    k_prep_n<<<(N + 255) / 256, 256, 0, stream>>>(atom_type, chir, c9map, deg, cursor,
                                                  Q, N);
    k_cntcomb<<<eb, 256, 0, stream>>>(ecol, deg, E, emb1, emb2, comb);
    k_bsum<<<NB, 256, 0, stream>>>(deg, bsum, N);
    k_indptr<<<NB, 256, 0, stream>>>(deg, bsum, indptr, N, NB);
    k_fill<<<eb, 256, 0, stream>>>(erow, ecol, etype, edir, indptr, cursor, packed, E);

    dim3 ggrid(2, (N + MT - 1) / MT);   // x = n-tile, y = m-tile
    int ab = (N + 7) / 8;
    float* banks[2] = {cs0, cs1};
    for (int l = 0; l < 5; l++) {
        float* wb = banks[l & 1];          // bank aggf(l) writes (wprep zeros it)
        float* rb = banks[(l + 1) & 1];    // bank wprep(l) reads (aggf(l-1)'s)
        k_wprep<<<SP, 320, 0, stream>>>(W + (size_t)l * EMB * EMB, rb,
                                        gamma + l * EMB - EMB, beta + l * EMB - EMB,
                                        l == 0 ? 1 : 0, N, Wt, srow, thr_bn, wb);
        if (l == 0)
            k_gemm<<<ggrid, 256, 0, stream>>>(comb, Wt, thr_bn, srow, Q, N, c9map);
        else
            k_gemm<<<ggrid, 256, 0, stream>>>(P, Wt, thr_bn, srow, Q, N, nullptr);
        k_aggf<<<ab, 320, 0, stream>>>(Q, indptr, packed, ee1 + l * 5, ee2 + l * 3, P,
                                       wb, N);
    }

    // layer-4 BN params (aggf(4) wrote bank 0) + group bounds, fused
    k_finbounds<<<(N + 320) / 320, 320, 0, stream>>>(batch, gstart, N, banks[0],
                                                     gamma + 4 * EMB, beta + 4 * EMB,
                                                     scale_bn, shift_bn);
    k_pool<<<NGRP / 8, 320, 0, stream>>>(P, scale_bn, shift_bn, gstart, hg);
    k_feat<<<NGRP / 16, 256, 0, stream>>>(hg, featW, featb, hf);
    k_head<<<NGRP / 8, 128, 0, stream>>>(hf, hW1, hb1, hW2, hb2, pred);
}

// Round 9
// 652.695 us; speedup vs baseline: 1.0692x; 1.0227x over previous
//
#include <hip/hip_runtime.h>
#include <math.h>

typedef unsigned short u16;
typedef unsigned int u32;
typedef short v8s __attribute__((ext_vector_type(8)));
typedef float v4f __attribute__((ext_vector_type(4)));

#define EMB 300
#define SP 320            // padded feature stride (bf16 elems)
#define NGRP 4096
#define FEAT 256
#define MT 96
#define NT 160
#define NCOMB 357         // 119 atom types x 3 chirality
#define NREP 32           // colstats replicas (atomic spread)
#define CSB (NREP * 2 * SP)   // floats per colstats bank

__device__ __forceinline__ u16 f2bf(float x) {
    u32 u = __float_as_uint(x);
    u += 0x7FFFu + ((u >> 16) & 1u);
    return (u16)(u >> 16);
}
__device__ __forceinline__ float bf2f(u16 h) {
    return __uint_as_float((u32)h << 16);
}
__device__ __forceinline__ void unpack8(uint4 w, float* o) {
    const u32* p = &w.x;
#pragma unroll
    for (int q = 0; q < 4; q++) {
        o[2 * q]     = __uint_as_float(p[q] << 16);
        o[2 * q + 1] = __uint_as_float(p[q] & 0xFFFF0000u);
    }
}
// clamp 8 packed bf16 against per-col bf16-exact thresholds (lossless repack)
// perm repack: dst = (lo>>16) | (hi & 0xFFFF0000)
__device__ __forceinline__ v8s clampA(uint4 w, float4 ta, float4 tb) {
    const u32* p = &w.x;
    float t[8] = {ta.x, ta.y, ta.z, ta.w, tb.x, tb.y, tb.z, tb.w};
    u32 o[4];
#pragma unroll
    for (int q = 0; q < 4; q++) {
        float lo = __uint_as_float(p[q] << 16);
        float hi = __uint_as_float(p[q] & 0xFFFF0000u);
        lo = fmaxf(lo, t[2 * q]);
        hi = fmaxf(hi, t[2 * q + 1]);
        o[q] = __builtin_amdgcn_perm(__float_as_uint(hi), __float_as_uint(lo),
                                     0x07060302u);
    }
    uint4 r = make_uint4(o[0], o[1], o[2], o[3]);
    return *(v8s*)&r;
}
// async global->LDS DMA, 16B per lane (dest = wave-uniform base + lane*16)
__device__ __forceinline__ void dma16(const u16* g, u16* l) {
    __builtin_amdgcn_global_load_lds(
        (const __attribute__((address_space(1))) unsigned int*)g,
        (__attribute__((address_space(3))) unsigned int*)l, 16, 0, 0);
}

// ---------- per-node prep: c9 map + zero deg/cursor + Q pad row --------------
__global__ void k_prep_n(const int* __restrict__ at, const int* __restrict__ ch,
                         int* __restrict__ c9, int* __restrict__ deg,
                         int* __restrict__ cursor, u16* __restrict__ Q, int N) {
    int n = blockIdx.x * blockDim.x + threadIdx.x;
    if (n < N) {
        c9[n] = at[n] * 3 + ch[n];
        deg[n] = 0;
        cursor[n] = 0;
    }
    // zero padding row Q[N] (gather target for out-of-range unroll slots)
    if (n < SP / 2) ((u32*)(Q + (size_t)N * SP))[n] = 0u;
}

// ---------- fused: edge count (CSR deg) + comb table build -------------------
__global__ void k_cntcomb(const int* __restrict__ col, int* __restrict__ deg, int E,
                          const float* __restrict__ e1, const float* __restrict__ e2,
                          u16* __restrict__ comb) {
    int i = blockIdx.x * blockDim.x + threadIdx.x;
    if (i < E) atomicAdd(&deg[col[i]], 1);
    if (i < NCOMB * 40) {
        int row = i / 40, f = i % 40;
        int at = row / 3, ch = row % 3;
        u32 o[4];
#pragma unroll
        for (int q = 0; q < 4; q++) {
            int c0 = f * 8 + q * 2;
            float x0 = 0.f, x1 = 0.f;
            if (c0 < EMB)     x0 = e1[(size_t)at * EMB + c0] + e2[(size_t)ch * EMB + c0];
            if (c0 + 1 < EMB) x1 = e1[(size_t)at * EMB + c0 + 1] + e2[(size_t)ch * EMB + c0 + 1];
            o[q] = (u32)f2bf(x0) | ((u32)f2bf(x1) << 16);
        }
        *(uint4*)(comb + (size_t)row * SP + f * 8) = make_uint4(o[0], o[1], o[2], o[3]);
    }
}

__global__ __launch_bounds__(256) void k_bsum(const int* __restrict__ deg,
                                              int* __restrict__ bsum, int N) {
    int base = blockIdx.x * 1024 + threadIdx.x * 4;
    int s = 0;
    if (base + 3 < N) {
        int4 v = *(const int4*)(deg + base);
        s = v.x + v.y + v.z + v.w;
    } else {
        for (int j = 0; j < 4; j++) if (base + j < N) s += deg[base + j];
    }
    __shared__ int red[256];
    red[threadIdx.x] = s;
    __syncthreads();
    for (int off = 128; off > 0; off >>= 1) {
        if (threadIdx.x < off) red[threadIdx.x] += red[threadIdx.x + off];
        __syncthreads();
    }
    if (threadIdx.x == 0) bsum[blockIdx.x] = red[0];
}

// indptr with block-offset scan fused in (each block redundantly scans bsum)
__global__ __launch_bounds__(256) void k_indptr(const int* __restrict__ deg,
                                                const int* __restrict__ bsum,
                                                int* __restrict__ indptr, int N, int NB) {
    __shared__ int bs[128];
    __shared__ int sh[256];
    int b = blockIdx.x, t = threadIdx.x;
    if (t < 128) bs[t] = (t < NB) ? bsum[t] : 0;
    __syncthreads();
    for (int off = 1; off < 128; off <<= 1) {
        int add = (t < 128 && t >= off) ? bs[t - off] : 0;
        __syncthreads();
        if (t < 128) bs[t] += add;
        __syncthreads();
    }
    int boffb = (b > 0) ? bs[b - 1] : 0;

    int base = b * 1024 + t * 4;
    int v[4] = {0, 0, 0, 0};
    if (base + 3 < N) {
        int4 w = *(const int4*)(deg + base);
        v[0] = w.x; v[1] = w.y; v[2] = w.z; v[3] = w.w;
    } else {
        for (int j = 0; j < 4; j++) if (base + j < N) v[j] = deg[base + j];
    }
    int tsum = v[0] + v[1] + v[2] + v[3];
    sh[t] = tsum;
    __syncthreads();
    for (int off = 1; off < 256; off <<= 1) {
        int add = (t >= off) ? sh[t - off] : 0;
        __syncthreads();
        sh[t] += add;
        __syncthreads();
    }
    int run = boffb + sh[t] - tsum;
    for (int j = 0; j < 4; j++) {
        run += v[j];
        if (base + j < N) indptr[base + j + 1] = run;
    }
    if (b == 0 && t == 0) indptr[0] = 0;
}

__global__ void k_fill(const int* __restrict__ row, const int* __restrict__ col,
                       const int* __restrict__ et, const int* __restrict__ ed,
                       const int* __restrict__ indptr, int* __restrict__ cursor,
                       int* __restrict__ packed, int E) {
    int e = blockIdx.x * blockDim.x + threadIdx.x;
    if (e >= E) return;
    int c = col[e];
    int pos = indptr[c] + atomicAdd(&cursor[c], 1);
    packed[pos] = row[e] | ((et[e] * 3 + ed[e]) << 17);
}

// ---- fused W prep: BN-finalize + Wt + srow + thr + zero next colstats bank --
__global__ __launch_bounds__(320) void k_wprep(
    const float* __restrict__ Wl, const float* __restrict__ cs,
    const float* __restrict__ gamma, const float* __restrict__ beta,
    int ident, int N, u16* __restrict__ Wt, float* __restrict__ srow,
    float* __restrict__ thr, float* __restrict__ wb) {
    __shared__ float wred[5];
    int n = blockIdx.x;
    int k = threadIdx.x;

    // zero the bank aggf(this layer) will write (blocks 0..63 cover CSB)
    int zi = n * 320 + k;
    if (zi < CSB) wb[zi] = 0.f;

    float scv, shv, thv;
    if (ident) {
        scv = (k < EMB) ? 1.f : 0.f;
        shv = 0.f;
        thv = -__builtin_inff();
    } else if (k < EMB) {
        float s1 = 0.f, s2 = 0.f;
        for (int r = 0; r < NREP; r++) {
            s1 += cs[r * 2 * SP + k];
            s2 += cs[r * 2 * SP + SP + k];
        }
        float inv = 1.f / (float)N;
        float mean = s1 * inv;
        float var = s2 * inv - mean * mean;
        float rstd = rsqrtf(fmaxf(var, 0.f) + 1e-5f);
        scv = gamma[k] * rstd;
        shv = beta[k] - mean * scv;
        thv = bf2f(f2bf(-shv / scv));
    } else {
        scv = 0.f; shv = 0.f; thv = -__builtin_inff();
    }
    if (n == 0) thr[k] = thv;

    float w = 0.f;
    if (n < EMB && k < EMB) w = Wl[(size_t)k * EMB + n];
    Wt[(size_t)n * SP + k] = f2bf(w * scv);
    float s = (k < EMB) ? shv * w : 0.f;
#pragma unroll
    for (int o2 = 32; o2 > 0; o2 >>= 1) s += __shfl_down(s, o2);
    if ((k & 63) == 0) wred[k >> 6] = s;
    __syncthreads();
    if (k == 0) {
        float t = wred[0] + wred[1] + wred[2] + wred[3] + wred[4];
        srow[n] = (n < EMB) ? t : 0.f;
    }
}

// ------------------- GEMM: Q = max(A[rowmap], thr) @ Wt + srow  ---------------
// v7: R8 kernel (MT=96, 32KB LDS, 5 blocks/CU) + bijective XCD swizzle (m204):
// 1D grid, n-tile inner, so each m-tile's two n-blocks and neighboring m-tiles
// land on the same XCD L2 (A-row re-reads and B panel become L2 hits, not L3).
__global__ __launch_bounds__(256) void k_gemm(
    const u16* __restrict__ A, const u16* __restrict__ Wt,
    const float* __restrict__ thr, const float* __restrict__ srow,
    u16* __restrict__ C, int M, const int* __restrict__ rowmap, int nwg) {
    __shared__ __align__(16) u16 sm[16384];   // A 2x3072 | B 2x5120 ; epi 96x168

    // bijective XCD swizzle: XCDs with id<r get q+1 consecutive wgs, rest q
    int wg = blockIdx.x;
    int q = nwg >> 3, r = nwg & 7;
    int xcd = wg & 7, idx = wg >> 3;
    int swz = (xcd < r ? xcd * (q + 1) : r * (q + 1) + (xcd - r) * q) + idx;
    int m0 = (swz >> 1) * MT;
    int n0 = (swz & 1) * NT;
    int tid = threadIdx.x;
    int wave = tid >> 6, lane = tid & 63;
    int wm = wave >> 1, wn = wave & 1;
    int lm = lane & 15, quad = lane >> 4;

    int ar0 = min(m0 + (tid >> 2), M - 1);
    int ar1 = min(m0 + 64 + (tid >> 2), M - 1);   // used by tid<128 (rows 64..95)
    if (rowmap) { ar0 = rowmap[ar0]; ar1 = rowmap[ar1]; }
    const u16* ag0 = A + (size_t)ar0 * SP + (tid & 3) * 8;
    const u16* ag1 = A + (size_t)ar1 * SP + (tid & 3) * 8;
    const u16* bg0 = Wt + (size_t)(n0 + (tid >> 2)) * SP + (tid & 3) * 8;
    const u16* bg1 = Wt + (size_t)(n0 + 64 + (tid >> 2)) * SP + (tid & 3) * 8;
    const u16* bg2 = Wt + (size_t)(n0 + 128 + (tid >> 2)) * SP + (tid & 3) * 8;

    const float* tp = thr + quad * 8;

    v4f acc[3][5];
#pragma unroll
    for (int nf = 0; nf < 5; nf++) {
        float sv = srow[n0 + wn * 80 + nf * 16 + lm];
#pragma unroll
        for (int mf = 0; mf < 3; mf++)
            acc[mf][nf] = (v4f){sv, sv, sv, sv};
    }

    auto issue = [&](int d, int kt) {
        int ko = kt * 32;
        u16* ad = sm + d * 3072;
        u16* bd = sm + 6144 + d * 5120;
        dma16(ag0 + ko, ad + tid * 8);                       // rows 0..63
        if (tid < 128) dma16(ag1 + ko, ad + (256 + tid) * 8); // rows 64..95
        dma16(bg0 + ko, bd + tid * 8);
        dma16(bg1 + ko, bd + (256 + tid) * 8);
        if (tid < 128) dma16(bg2 + ko, bd + (512 + tid) * 8);
    };

    issue(0, 0);
    for (int kt = 0; kt < SP / 32; kt++) {
        __syncthreads();                      // drains this ktile's DMA
        if (kt + 1 < SP / 32) issue((kt + 1) & 1, kt + 1);
        const u16* as = sm + (kt & 1) * 3072;
        const u16* bs = sm + 6144 + (kt & 1) * 5120;
        float4 ta = *(const float4*)(tp + kt * 32);
        float4 tb = *(const float4*)(tp + kt * 32 + 4);
        v8s b[5], a[3];
#pragma unroll
        for (int nf = 0; nf < 5; nf++)
            b[nf] = *(const v8s*)(bs + (wn * 80 + nf * 16 + lm) * 32 + quad * 8);
#pragma unroll
        for (int mf = 0; mf < 3; mf++) {
            uint4 w = *(const uint4*)(as + (wm * 48 + mf * 16 + lm) * 32 + quad * 8);
            a[mf] = clampA(w, ta, tb);
        }
#pragma unroll
        for (int nf = 0; nf < 5; nf++)
#pragma unroll
            for (int mf = 0; mf < 3; mf++)
                acc[mf][nf] = __builtin_amdgcn_mfma_f32_16x16x32_bf16(a[mf], b[nf], acc[mf][nf], 0, 0, 0);
    }

    __syncthreads();                          // staging reads done -> overlay
#pragma unroll
    for (int mf = 0; mf < 3; mf++)
#pragma unroll
        for (int nf = 0; nf < 5; nf++)
#pragma unroll
            for (int r2 = 0; r2 < 4; r2++)
                sm[(wm * 48 + mf * 16 + quad * 4 + r2) * 168 + wn * 80 + nf * 16 + lm] =
                    f2bf(acc[mf][nf][r2]);
    __syncthreads();
#pragma unroll
    for (int i = 0; i < 8; i++) {
        int slot = tid + i * 256;             // 1920 slots = 96 rows x 20 cgroups
        if (slot < 1920) {
            int lr = slot / 20, cg = slot % 20;
            int grow = m0 + lr;
            if (grow < M)
                *(uint4*)(C + (size_t)grow * SP + n0 + cg * 8) =
                    *(const uint4*)(sm + lr * 168 + cg * 8);
        }
    }
}

// ---- aggregate + fused BN stats, flat one-node-per-slot, 4-deep gather -------
__global__ __launch_bounds__(320) void k_aggf(
    const u16* __restrict__ Q, const int* __restrict__ indptr,
    const int* __restrict__ packed, const float* __restrict__ e1,
    const float* __restrict__ e2, u16* __restrict__ P,
    float* __restrict__ colstats, int N) {
    __shared__ float tab[16];
    __shared__ float part[8][328];
    int tid = threadIdx.x;
    int f = tid % 40;
    int slot = tid / 40;
    int n = blockIdx.x * 8 + slot;
    int nn = min(n, N - 1);

    // early independent loads: self row + CSR range (latency overlaps tab setup)
    uint4 sg = *(const uint4*)(Q + (size_t)nn * SP + f * 8);
    int i = indptr[nn];
    int e = indptr[nn + 1];

    if (tid < 16) tab[tid] = (tid < 15) ? e1[tid / 3] + e2[tid % 3] : 0.f;
    __syncthreads();

    float psum[8] = {0, 0, 0, 0, 0, 0, 0, 0};
    float psq[8]  = {0, 0, 0, 0, 0, 0, 0, 0};

    if (n < N) {
        const int PKZ = N | (15 << 17);     // padding row, zero edge weight
        float acc[8];
        unpack8(sg, acc);
        float s = tab[12];                  // self loop: et=4, ed=0 -> code 12
        while (i < e) {
            int pk0 = packed[i];
            int pk1 = (i + 1 < e) ? packed[i + 1] : PKZ;
            int pk2 = (i + 2 < e) ? packed[i + 2] : PKZ;
            int pk3 = (i + 3 < e) ? packed[i + 3] : PKZ;
            uint4 g0 = *(const uint4*)(Q + (size_t)(pk0 & 0x1FFFF) * SP + f * 8);
            uint4 g1 = *(const uint4*)(Q + (size_t)(pk1 & 0x1FFFF) * SP + f * 8);
            uint4 g2 = *(const uint4*)(Q + (size_t)(pk2 & 0x1FFFF) * SP + f * 8);
            uint4 g3 = *(const uint4*)(Q + (size_t)(pk3 & 0x1FFFF) * SP + f * 8);
            float t[8];
            unpack8(g0, t);
#pragma unroll
            for (int q = 0; q < 8; q++) acc[q] += t[q];
            unpack8(g1, t);
#pragma unroll
            for (int q = 0; q < 8; q++) acc[q] += t[q];
            unpack8(g2, t);
#pragma unroll
            for (int q = 0; q < 8; q++) acc[q] += t[q];
            unpack8(g3, t);
#pragma unroll
            for (int q = 0; q < 8; q++) acc[q] += t[q];
            s += tab[pk0 >> 17] + tab[pk1 >> 17] + tab[pk2 >> 17] + tab[pk3 >> 17];
            i += 4;
        }
        u32 o[4];
#pragma unroll
        for (int q = 0; q < 4; q++) {
            float r0 = acc[2 * q] + s;
            float r1 = acc[2 * q + 1] + s;
            psum[2 * q] = r0;      psum[2 * q + 1] = r1;
            psq[2 * q]  = r0 * r0; psq[2 * q + 1]  = r1 * r1;
            o[q] = (u32)f2bf(r0) | ((u32)f2bf(r1) << 16);
        }
        *(uint4*)(P + (size_t)n * SP + f * 8) = make_uint4(o[0], o[1], o[2], o[3]);
    }

    int rep = (blockIdx.x & (NREP - 1)) * 2 * SP;
#pragma unroll
    for (int j = 0; j < 8; j++) part[slot][f * 8 + j] = psum[j];
    __syncthreads();
    {
        float s = 0.f;
#pragma unroll
        for (int k = 0; k < 8; k++) s += part[k][tid];
        atomicAdd(&colstats[rep + tid], s);
    }
    __syncthreads();
#pragma unroll
    for (int j = 0; j < 8; j++) part[slot][f * 8 + j] = psq[j];
    __syncthreads();
    {
        float s = 0.f;
#pragma unroll
        for (int k = 0; k < 8; k++) s += part[k][tid];
        atomicAdd(&colstats[rep + SP + tid], s);
    }
}

// ---- fused: group boundaries from sorted batch + layer-4 BN params ----------
__global__ __launch_bounds__(320) void k_finbounds(
    const int* __restrict__ batch, int* __restrict__ gstart, int N,
    const float* __restrict__ cs, const float* __restrict__ gamma,
    const float* __restrict__ beta, float* __restrict__ sc, float* __restrict__ sh) {
    int t = threadIdx.x;
    int n = blockIdx.x * 320 + t;
    if (n <= N) {
        int bcur = (n < N) ? batch[n] : NGRP;
        int bprev = (n > 0) ? batch[n - 1] : -1;
        for (int g = bprev + 1; g <= bcur; g++) gstart[g] = n;
    }
    if (blockIdx.x == 0 && t < SP) {
        float s1 = 0.f, s2 = 0.f;
        for (int r = 0; r < NREP; r++) {
            s1 += cs[r * 2 * SP + t];
            s2 += cs[r * 2 * SP + SP + t];
        }
        if (t < EMB) {
            float inv = 1.f / (float)N;
            float mean = s1 * inv;
            float var = s2 * inv - mean * mean;
            float rstd = rsqrtf(fmaxf(var, 0.f) + 1e-5f);
            float s = gamma[t] * rstd;
            sc[t] = s;
            sh[t] = beta[t] - mean * s;
        } else {
            sc[t] = 0.f; sh[t] = 0.f;
        }
    }
}

// ------------------- pool (BN layer4 fused, no relu), 8 groups/block ----------
__global__ __launch_bounds__(320) void k_pool(
    const u16* __restrict__ P, const float* __restrict__ sc,
    const float* __restrict__ sh, const int* __restrict__ gstart,
    float* __restrict__ hg) {
    int tid = threadIdx.x;
    int g = blockIdx.x * 8 + tid / 40;
    int f = tid % 40;
    int r0 = gstart[g], r1 = gstart[g + 1];
    int cnt = r1 - r0;
    float acc[8] = {0, 0, 0, 0, 0, 0, 0, 0};
    for (int r = r0; r < r1; r++) {
        float t[8];
        unpack8(*(const uint4*)(P + (size_t)r * SP + f * 8), t);
#pragma unroll
        for (int j = 0; j < 8; j++) acc[j] += t[j];
    }
    float inv = 1.f / (float)max(cnt, 1);
#pragma unroll
    for (int j = 0; j < 8; j++) {
        int c = f * 8 + j;
        if (c < EMB)
            hg[(size_t)g * EMB + c] = (acc[j] * sc[c] + (float)cnt * sh[c]) * inv;
    }
}

// ------------------- hf = hg @ feat_W + feat_b -------------------
__global__ __launch_bounds__(256) void k_feat(const float* __restrict__ hg,
                                              const float* __restrict__ fW,
                                              const float* __restrict__ fb,
                                              float* __restrict__ hf) {
    __shared__ float hgs[16 * EMB];
    int g0 = blockIdx.x * 16;
    int tid = threadIdx.x;
    for (int i = tid; i < 16 * EMB; i += 256) {
        int gi = i / EMB, c = i % EMB;
        hgs[i] = hg[(size_t)(g0 + gi) * EMB + c];
    }
    __syncthreads();
    float acc[16];
    float fbv = fb[tid];
#pragma unroll
    for (int gi = 0; gi < 16; gi++) acc[gi] = fbv;
    for (int k = 0; k < EMB; k++) {
        float w = fW[(size_t)k * FEAT + tid];
#pragma unroll
        for (int gi = 0; gi < 16; gi++) acc[gi] += hgs[gi * EMB + k] * w;
    }
#pragma unroll
    for (int gi = 0; gi < 16; gi++) hf[(size_t)(g0 + gi) * FEAT + tid] = acc[gi];
}

// ------------------- head: pred = softplus(hf@W1+b1)@W2+b2 -------------------
__global__ __launch_bounds__(128) void k_head(const float* __restrict__ hf,
                                              const float* __restrict__ W1,
                                              const float* __restrict__ b1,
                                              const float* __restrict__ W2,
                                              const float* __restrict__ b2,
                                              float* __restrict__ pred) {
    __shared__ float hfs[8 * FEAT];
    __shared__ float sred[2][8][2];
    int g0 = blockIdx.x * 8;
    int tid = threadIdx.x;
    for (int i = tid; i < 8 * FEAT; i += 128) {
        int gi = i >> 8, k = i & 255;
        hfs[i] = hf[(size_t)(g0 + gi) * FEAT + k];
    }
    __syncthreads();
    float acc[8];
    float b1v = b1[tid];
#pragma unroll
    for (int gi = 0; gi < 8; gi++) acc[gi] = b1v;
    for (int k = 0; k < FEAT; k++) {
        float w = W1[(size_t)k * 128 + tid];
#pragma unroll
        for (int gi = 0; gi < 8; gi++) acc[gi] += hfs[gi * FEAT + k] * w;
    }
    float w20 = W2[tid * 2], w21 = W2[tid * 2 + 1];
    int wv = tid >> 6;
#pragma unroll
    for (int gi = 0; gi < 8; gi++) {
        float x = acc[gi];
        float t = fmaxf(x, 0.f) + log1pf(expf(-fabsf(x)));
        float p0 = t * w20, p1 = t * w21;
#pragma unroll
        for (int off = 32; off > 0; off >>= 1) {
            p0 += __shfl_down(p0, off);
            p1 += __shfl_down(p1, off);
        }
        if ((tid & 63) == 0) { sred[wv][gi][0] = p0; sred[wv][gi][1] = p1; }
    }
    __syncthreads();
    if (tid < 16) {
        int gi = tid >> 1, o = tid & 1;
        pred[(size_t)(g0 + gi) * 2 + o] = sred[0][gi][o] + sred[1][gi][o] + b2[o];
    }
}

// ------------------- launch -------------------
extern "C" void kernel_launch(void* const* d_in, const int* in_sizes, int n_in,
                              void* d_out, int out_size, void* d_ws, size_t ws_size,
                              hipStream_t stream) {
    const int* atom_type = (const int*)d_in[0];
    const int* chir      = (const int*)d_in[1];
    const int* eidx      = (const int*)d_in[2];
    const int* etype     = (const int*)d_in[3];
    const int* edir      = (const int*)d_in[4];
    const int* batch     = (const int*)d_in[5];
    const float* emb1    = (const float*)d_in[6];
    const float* emb2    = (const float*)d_in[7];
    const float* W       = (const float*)d_in[8];
    const float* ee1     = (const float*)d_in[10];
    const float* ee2     = (const float*)d_in[11];
    const float* gamma   = (const float*)d_in[12];
    const float* beta    = (const float*)d_in[13];
    const float* featW   = (const float*)d_in[14];
    const float* featb   = (const float*)d_in[15];
    const float* hW1     = (const float*)d_in[16];
    const float* hb1     = (const float*)d_in[17];
    const float* hW2     = (const float*)d_in[18];
    const float* hb2     = (const float*)d_in[19];

    int N = in_sizes[0];
    int E = in_sizes[2] / 2;
    const int* erow = eidx;
    const int* ecol = eidx + E;

    size_t off = 0;
    char* base = (char*)d_ws;
    auto carve = [&](size_t bytes) -> void* {
        void* p = base + off;
        off += (bytes + 255) & ~(size_t)255;
        return p;
    };
    u16*   P        = (u16*)  carve((size_t)(N + 1) * SP * 2);
    u16*   Q        = (u16*)  carve((size_t)(N + 1) * SP * 2);
    u16*   Wt       = (u16*)  carve((size_t)SP * SP * 2);
    u16*   comb     = (u16*)  carve((size_t)NCOMB * SP * 2);
    int*   c9map    = (int*)  carve((size_t)N * 4);
    int*   deg      = (int*)  carve((size_t)N * 4);
    int*   cursor   = (int*)  carve((size_t)N * 4);
    int*   indptr   = (int*)  carve((size_t)(N + 1) * 4);
    int*   packed   = (int*)  carve((size_t)(E + 8) * 4);
    int*   bsum     = (int*)  carve(1024 * 4);
    float* cs0      = (float*)carve((size_t)CSB * 4);   // colstats bank 0
    float* cs1      = (float*)carve((size_t)CSB * 4);   // colstats bank 1
    float* scale_bn = (float*)carve(SP * 4);
    float* shift_bn = (float*)carve(SP * 4);
    float* thr_bn   = (float*)carve(SP * 4);
    float* srow     = (float*)carve(SP * 4);
    int*   gstart   = (int*)  carve((size_t)(NGRP + 1) * 4);
    float* hg       = (float*)carve((size_t)NGRP * EMB * 4);

    float* hf   = (float*)d_out;
    float* pred = (float*)d_out + (size_t)NGRP * FEAT;

    int eb = (E + 255) / 256;
    int NB = (N + 1023) / 1024;
    k_prep_n<<<(N + 255) / 256, 256, 0, stream>>>(atom_type, chir, c9map, deg, cursor,
                                                  Q, N);
    k_cntcomb<<<eb, 256, 0, stream>>>(ecol, deg, E, emb1, emb2, comb);
    k_bsum<<<NB, 256, 0, stream>>>(deg, bsum, N);
    k_indptr<<<NB, 256, 0, stream>>>(deg, bsum, indptr, N, NB);
    k_fill<<<eb, 256, 0, stream>>>(erow, ecol, etype, edir, indptr, cursor, packed, E);

    int nwg = 2 * ((N + MT - 1) / MT);   // 1D grid, XCD-swizzled inside kernel
    int ab = (N + 7) / 8;
    float* banks[2] = {cs0, cs1};
    for (int l = 0; l < 5; l++) {
        float* wb = banks[l & 1];          // bank aggf(l) writes (wprep zeros it)
        float* rb = banks[(l + 1) & 1];    // bank wprep(l) reads (aggf(l-1)'s)
        k_wprep<<<SP, 320, 0, stream>>>(W + (size_t)l * EMB * EMB, rb,
                                        gamma + l * EMB - EMB, beta + l * EMB - EMB,
                                        l == 0 ? 1 : 0, N, Wt, srow, thr_bn, wb);
        if (l == 0)
            k_gemm<<<nwg, 256, 0, stream>>>(comb, Wt, thr_bn, srow, Q, N, c9map, nwg);
        else
            k_gemm<<<nwg, 256, 0, stream>>>(P, Wt, thr_bn, srow, Q, N, nullptr, nwg);
        k_aggf<<<ab, 320, 0, stream>>>(Q, indptr, packed, ee1 + l * 5, ee2 + l * 3, P,
                                       wb, N);
    }

    // layer-4 BN params (aggf(4) wrote bank 0) + group bounds, fused
    k_finbounds<<<(N + 320) / 320, 320, 0, stream>>>(batch, gstart, N, banks[0],
                                                     gamma + 4 * EMB, beta + 4 * EMB,
                                                     scale_bn, shift_bn);
    k_pool<<<NGRP / 8, 320, 0, stream>>>(P, scale_bn, shift_bn, gstart, hg);
    k_feat<<<NGRP / 16, 256, 0, stream>>>(hg, featW, featb, hf);
    k_head<<<NGRP / 8, 128, 0, stream>>>(hf, hW1, hb1, hW2, hb2, pred);
}